// Round 5
// baseline (251.716 us; speedup 1.0000x reference)
//
#include <hip/hip_runtime.h>
#include <math.h>

#define NG 512
#define NP 128
#define HID 64
#define KNN 24
#define NTOT (NG*NP)

typedef __attribute__((ext_vector_type(8)))  short  short8;
typedef __attribute__((ext_vector_type(16))) float  floatx16;

__device__ __forceinline__ float elu_f(float v) {
    const float e = __builtin_amdgcn_exp2f(v * 1.442695040888963f) - 1.0f;
    return v > 0.0f ? v : e;
}

__device__ __forceinline__ void split_bf16(float x, unsigned short& hb, unsigned short& lb) {
    unsigned u = __float_as_uint(x);
    unsigned h = (u + 0x7FFFu + ((u >> 16) & 1u)) >> 16;
    hb = (unsigned short)h;
    float hf = __uint_as_float(h << 16);
    float lo = x - hf;
    unsigned v = __float_as_uint(lo);
    lb = (unsigned short)((v + 0x7FFFu + ((v >> 16) & 1u)) >> 16);
}
__device__ __forceinline__ unsigned short bf_rne(float x) {
    unsigned u = __float_as_uint(x);
    return (unsigned short)((u + 0x7FFFu + ((u >> 16) & 1u)) >> 16);
}
__device__ __forceinline__ float bf_lo(unsigned u) { return __uint_as_float(u << 16); }
__device__ __forceinline__ float bf_hi(unsigned u) { return __uint_as_float(u & 0xFFFF0000u); }

// order-preserving bf16 <-> u16 key map (monotone: unsigned compare == float compare)
__device__ __forceinline__ unsigned short f_to_key(unsigned short b) {
    return (unsigned short)(b ^ ((b & 0x8000u) ? 0xFFFFu : 0x8000u));
}
__device__ __forceinline__ float key_to_f(unsigned k) {
    const unsigned bf = (k & 0x8000u) ? (k ^ 0x8000u) : (k ^ 0xFFFFu);
    return __uint_as_float(bf << 16);
}
__device__ __forceinline__ unsigned pk_max_u16(unsigned a, unsigned b) {
    unsigned d;
    asm("v_pk_max_u16 %0, %1, %2" : "=v"(d) : "v"(a), "v"(b));
    return d;
}

// XOR-swizzled hilo accessor: row = 16 chunks of 16B (hi ch 0..7, lo ch 8..15).
__device__ __forceinline__ unsigned short* hchunk(unsigned short* base, int row, int ch) {
    return base + (((row << 4) + (ch ^ (row & 15))) << 3);
}
__device__ __forceinline__ const unsigned short* hchunk(const unsigned short* base, int row, int ch) {
    return base + (((row << 4) + (ch ^ (row & 15))) << 3);
}

// bitonic sort 8 ascending
__device__ __forceinline__ void sort8_asc(unsigned* y) {
    #pragma unroll
    for (int k = 2; k <= 8; k <<= 1)
        #pragma unroll
        for (int j = k >> 1; j > 0; j >>= 1)
            #pragma unroll
            for (int i = 0; i < 8; ++i) {
                const int l = i ^ j;
                if (l > i) {
                    const bool up = ((i & k) == 0);
                    const unsigned a = y[i], b = y[l];
                    const unsigned mn = a < b ? a : b;
                    const unsigned mx = a < b ? b : a;
                    y[i] = up ? mn : mx;
                    y[l] = up ? mx : mn;
                }
            }
}

// x[0..23] asc ++ x[24..31] desc (bitonic) -> keep smallest 24 sorted
__device__ __forceinline__ void merge_top24(unsigned* x) {
    #pragma unroll
    for (int d = 16; d > 0; d >>= 1)
        #pragma unroll
        for (int i = 0; i < 32; ++i)
            if (!(i & d) && i < 24) {
                const int l = i | d;
                const unsigned a = x[i], b = x[l];
                x[i] = a < b ? a : b;
                x[l] = a < b ? b : a;
            }
}

// merge my sorted-24 list with lane (lane^mask)'s sorted-24 list, keep smallest 24.
__device__ __forceinline__ void merge2_shfl(unsigned* xk, int mask) {
    unsigned z[32];
    #pragma unroll
    for (int e = 0; e < 24; ++e) {
        const unsigned ye = (unsigned)__shfl_xor((int)xk[23 - e], mask);
        z[8 + e] = xk[e] < ye ? xk[e] : ye;
    }
    #pragma unroll
    for (int d = 16; d > 0; d >>= 1)
        #pragma unroll
        for (int i = 8; i < 32; ++i)
            if (!(i & d)) {
                const int l = i | d;
                const unsigned a = z[i], b = z[l];
                z[i] = a < b ? a : b;
                z[l] = a < b ? b : a;
            }
    #pragma unroll
    for (int e = 0; e < 24; ++e) xk[e] = z[8 + e];
}

// ---------------- pack weights into MFMA-B-fragment-ready hi/lo bf16 layout ----------------
__global__ __launch_bounds__(256) void pack_w(
    const float* __restrict__ wc1, const float* __restrict__ wc2, const float* __restrict__ wc3,
    const float* __restrict__ we2,
    unsigned short* __restrict__ wp)
{
    const int n = blockIdx.x*256 + threadIdx.x;      // 0..28671
    if (n < 24576) {
        const int layer = n >> 13;
        const int r = n & 8191;
        const int e = r & 7, j = (r >> 3) & 127, ch = r >> 10;
        const int k = (ch >> 1)*16 + (ch & 1)*8 + e;
        const float* wc = (layer == 0) ? wc1 : ((layer == 1) ? wc2 : wc3);
        float w;
        if (j < 64) w = wc[k*64 + j] - wc[(k+64)*64 + j];
        else        w = wc[(k+64)*64 + (j-64)];
        unsigned short hb, lb;
        split_bf16(w, hb, lb);
        unsigned short* base = wp + layer*16384;
        base[r] = hb;
        base[8192 + r] = lb;
    } else if (n < 24576 + 4096) {
        const int m = n - 24576;
        const int e = m & 7, col = (m >> 3) & 63, ch = m >> 9;
        const int k = (ch >> 1)*16 + (ch & 1)*8 + e;
        unsigned short hb, lb;
        split_bf16(we2[k*64 + col], hb, lb);
        unsigned short* base = wp + 49152;
        base[m] = hb;
        base[4096 + m] = lb;
    }
}

// ---------------- single fused kernel: encoder + 3 conv layers + pooling + head MLP ----------------
// 512 threads (8 waves), one graph per block. Grid=512 => 2 blocks/CU; LDS up to 80KB free.
// Arena (69632 B):
//   keys  [128][65] u32 @0      (33280; aliases prologue staging, bs key-bf16[128][68] in ab/agg)
//   nnidx [128][6]  u32 @33280  ( 3072; aliases pool8[8][64] @33280 + head scratch @35328 in epilogue)
//   hilo  swizzled bf16 @36352  (32768)
//   sqs   [128] f32 @69120      (  512)
__global__ __launch_bounds__(512, 4) void conv_all(
    const float* __restrict__ x,
    const unsigned short* __restrict__ wp,
    const float* __restrict__ bc1, const float* __restrict__ bc2, const float* __restrict__ bc3,
    const float* __restrict__ we1, const float* __restrict__ be1,
    const unsigned short* __restrict__ we2p, const float* __restrict__ be2,
    const float* __restrict__ wo1, const float* __restrict__ bo1,
    const float* __restrict__ wo2, const float* __restrict__ bo2,
    const float* __restrict__ wo3, const float* __restrict__ bo3,
    const float* __restrict__ wo4, const float* __restrict__ bo4,
    const float* __restrict__ wo5, const float* __restrict__ bo5,
    float* __restrict__ ag_all, float* __restrict__ outp, float* __restrict__ out_batch)
{
    __shared__ __align__(16) char arena[69632];
    unsigned*        keys  = (unsigned*)arena;
    unsigned*        nnidx = (unsigned*)(arena + 33280);
    unsigned short*  hilo  = (unsigned short*)(arena + 36352);
    float*           sqs   = (float*)(arena + 69120);

    const int g = blockIdx.x;
    const int t = threadIdx.x;
    const int w = t >> 6, lane = t & 63;
    const int lj = lane & 31, half = lane >> 5;
    const int rt = w & 3, wg = w >> 2;
    float* __restrict__ ag = ag_all + (size_t)g * (NP*HID);

    // ================= encoder prologue =================
    {
        float* w1s = (float*)arena;            // [4][64]
        float* b1v = (float*)(arena + 1024);   // [64]
        float* b2v = (float*)(arena + 1280);   // [64]
        if (t < 256) w1s[t] = we1[t];
        else if (t < 320) b1v[t-256] = be1[t-256];
        else if (t < 384) b2v[t-320] = be2[t-320];
        if (t < 128) out_batch[(size_t)g*128 + t] = (float)g;
        __syncthreads();

        // layer 1: n = node, fh = col-half (32 cols via 16-wide quarters)
        const int n = t & 127, fh = t >> 7, f0 = fh*16;
        const float4 xv = ((const float4*)x)[g*128 + n];
        float acc1[16];
        #pragma unroll
        for (int q = 0; q < 4; ++q) {
            const float4 b4 = *(const float4*)(b1v + f0 + q*4);
            acc1[q*4+0] = b4.x; acc1[q*4+1] = b4.y; acc1[q*4+2] = b4.z; acc1[q*4+3] = b4.w;
        }
        #pragma unroll
        for (int k = 0; k < 4; ++k) {
            const float xk_ = (k == 0) ? xv.x : (k == 1) ? xv.y : (k == 2) ? xv.z : xv.w;
            #pragma unroll
            for (int q = 0; q < 4; ++q) {
                const float4 w4 = *(const float4*)(w1s + k*64 + f0 + q*4);
                acc1[q*4+0] = fmaf(xk_, w4.x, acc1[q*4+0]);
                acc1[q*4+1] = fmaf(xk_, w4.y, acc1[q*4+1]);
                acc1[q*4+2] = fmaf(xk_, w4.z, acc1[q*4+2]);
                acc1[q*4+3] = fmaf(xk_, w4.w, acc1[q*4+3]);
            }
        }
        unsigned hu[8], lu[8];
        #pragma unroll
        for (int e = 0; e < 8; ++e) {
            const float v0 = elu_f(acc1[2*e]), v1 = elu_f(acc1[2*e+1]);
            unsigned short h0, l0, h1, l1;
            split_bf16(v0, h0, l0); split_bf16(v1, h1, l1);
            hu[e] = (unsigned)h0 | ((unsigned)h1 << 16);
            lu[e] = (unsigned)l0 | ((unsigned)l1 << 16);
        }
        *(uint4*)hchunk(hilo, n, fh*2)       = make_uint4(hu[0], hu[1], hu[2], hu[3]);
        *(uint4*)hchunk(hilo, n, fh*2 + 1)   = make_uint4(hu[4], hu[5], hu[6], hu[7]);
        *(uint4*)hchunk(hilo, n, 8 + fh*2)   = make_uint4(lu[0], lu[1], lu[2], lu[3]);
        *(uint4*)hchunk(hilo, n, 8 + fh*2+1) = make_uint4(lu[4], lu[5], lu[6], lu[7]);
        __syncthreads();

        // layer 2 via MFMA: 8 tiles = (rt, jt2=wg), loads interleaved with MFMAs
        const int jt2 = wg;
        floatx16 acc = {0.f,0.f,0.f,0.f,0.f,0.f,0.f,0.f,0.f,0.f,0.f,0.f,0.f,0.f,0.f,0.f};
        #pragma unroll
        for (int p = 0; p < 3; ++p) {
            const int aSel = (p == 2) ? 8 : 0;
            const int part = (p == 1) ? 1 : 0;
            #pragma unroll
            for (int c = 0; c < 4; ++c) {
                const short8 af  = *(const short8*)hchunk(hilo, rt*32 + lj, aSel + c*2 + half);
                const short8 bf4 = *(const short8*)((const short*)we2p + part*4096 + (((c*2 + half)*64) + jt2*32 + lj)*8);
                acc = __builtin_amdgcn_mfma_f32_32x32x16_bf16(af, bf4, acc, 0, 0, 0);
            }
        }
        const int col = jt2*32 + lj;
        const float bias = ((const float*)(arena + 1280))[col];
        __syncthreads();   // all layer-2 hilo reads done before overwrite
        #pragma unroll
        for (int reg = 0; reg < 16; ++reg) {
            const int row = (reg & 3) + 8*(reg >> 2) + 4*half + rt*32;
            const float v = elu_f(acc[reg] + bias);
            unsigned short hb, lb;
            split_bf16(v, hb, lb);
            *(hchunk(hilo, row, col >> 3) + (col & 7))       = hb;
            *(hchunk(hilo, row, 8 + (col >> 3)) + (col & 7)) = lb;
        }
        __syncthreads();

        // sq read-back: r = node, cq = col-quarter
        const int r = t >> 2, cq = t & 3, c0 = cq*2;
        const uint4 h0 = *(const uint4*)hchunk(hilo, r, c0);
        const uint4 h1 = *(const uint4*)hchunk(hilo, r, c0+1);
        const uint4 l0 = *(const uint4*)hchunk(hilo, r, 8+c0);
        const uint4 l1 = *(const uint4*)hchunk(hilo, r, 8+c0+1);
        float s = 0.0f;
        const unsigned hh[8] = {h0.x,h0.y,h0.z,h0.w,h1.x,h1.y,h1.z,h1.w};
        const unsigned ll[8] = {l0.x,l0.y,l0.z,l0.w,l1.x,l1.y,l1.z,l1.w};
        #pragma unroll
        for (int e = 0; e < 8; ++e) {
            const float va = bf_lo(hh[e]) + bf_lo(ll[e]);
            const float vb = bf_hi(hh[e]) + bf_hi(ll[e]);
            s = fmaf(va, va, s); s = fmaf(vb, vb, s);
        }
        s += __shfl_xor(s, 1);
        s += __shfl_xor(s, 2);
        if (cq == 0) sqs[r] = s;
        __syncthreads();
    }

    // ================= 3 conv layers =================
    #pragma unroll 1
    for (int L = 0; L < 3; ++L) {
        const unsigned short* wpl = wp + L*16384;
        const float* bcl = (L == 0) ? bc1 : (L == 1) ? bc2 : bc3;

        // ---- Gram rounds (2 tiles/round, all 8 waves); keys computed pre-barrier for overlap ----
        unsigned xk[32];
        #pragma unroll
        for (int s = 0; s < 24; ++s) xk[s] = 0xFFFFFFFFu;

        #pragma unroll 1
        for (int r = 0; r < 2; ++r) {
            const int jt = r*2 + wg;
            unsigned kv[16];
            {
                floatx16 acc = {0.f,0.f,0.f,0.f,0.f,0.f,0.f,0.f,0.f,0.f,0.f,0.f,0.f,0.f,0.f,0.f};
                #pragma unroll
                for (int p = 0; p < 3; ++p) {
                    const int aSel = (p == 2) ? 8 : 0;
                    const int bSel = (p == 1) ? 8 : 0;
                    #pragma unroll
                    for (int c = 0; c < 4; ++c) {
                        const short8 af = *(const short8*)hchunk(hilo, rt*32 + lj, aSel + c*2 + half);
                        const short8 bf = *(const short8*)hchunk(hilo, jt*32 + lj, bSel + c*2 + half);
                        acc = __builtin_amdgcn_mfma_f32_32x32x16_bf16(af, bf, acc, 0, 0, 0);
                    }
                }
                const unsigned jg = (unsigned)(jt*32 + lj);
                const float sqj = sqs[jg];
                #pragma unroll
                for (int reg = 0; reg < 16; ++reg) {
                    const int i = (reg & 3) + 8*(reg >> 2) + 4*half + rt*32;
                    float d = fmaf(-2.0f, acc[reg], sqs[i] + sqj);
                    d = fmaxf(d, 0.0f);
                    kv[reg] = (__float_as_uint(d) & 0xFFFFFF80u) | jg;
                }
            }
            if (r == 1) __syncthreads();   // round-0 sort reads of keys done before overwrite
            #pragma unroll
            for (int reg = 0; reg < 16; ++reg) {
                const int i = (reg & 3) + 8*(reg >> 2) + 4*half + rt*32;
                keys[i*65 + wg*32 + lj] = kv[reg];
            }
            __syncthreads();               // keys ready
            {
                // sort ownership: row = t>>2, seg = t&3 -> absorb 16 new keys
                const unsigned* kr = keys + (t >> 2)*65 + (t & 3)*16;
                const uint4 k0 = *(const uint4*)kr;
                const uint4 k1 = *(const uint4*)(kr + 4);
                {
                    unsigned y[8] = {k0.x, k0.y, k0.z, k0.w, k1.x, k1.y, k1.z, k1.w};
                    sort8_asc(y);
                    #pragma unroll
                    for (int e = 0; e < 8; ++e) xk[24+e] = y[7-e];
                    merge_top24(xk);
                }
                const uint4 k2 = *(const uint4*)(kr + 8);
                const uint4 k3 = *(const uint4*)(kr + 12);
                {
                    unsigned y[8] = {k2.x, k2.y, k2.z, k2.w, k3.x, k3.y, k3.z, k3.w};
                    sort8_asc(y);
                    #pragma unroll
                    for (int e = 0; e < 8; ++e) xk[24+e] = y[7-e];
                    merge_top24(xk);
                }
            }
        }

        // ---- cross-lane tree merge + nnidx (register-only; no barrier yet) ----
        merge2_shfl(xk, 1);
        merge2_shfl(xk, 2);
        if ((t & 3) == 0) {
            #pragma unroll
            for (int c = 0; c < 6; ++c)
                nnidx[(t >> 2)*6 + c] = (xk[c*4] & 127u) | ((xk[c*4+1] & 127u) << 8)
                                      | ((xk[c*4+2] & 127u) << 16) | ((xk[c*4+3] & 127u) << 24);
        }

        // ---- ab-GEMM: compute BEFORE the keys-drain barrier; wg1 stashes acc, writes bs after ----
        unsigned short* bs = (unsigned short*)arena;   // [128][68] order-key bf16
        {
            floatx16 accs0, accs1;
            #pragma unroll 1
            for (int q2 = 0; q2 < 2; ++q2) {
                const int jt = wg*2 + q2;
                floatx16 acc = {0.f,0.f,0.f,0.f,0.f,0.f,0.f,0.f,0.f,0.f,0.f,0.f,0.f,0.f,0.f,0.f};
                short8 bfh[4];
                #pragma unroll
                for (int c = 0; c < 4; ++c)
                    bfh[c] = *(const short8*)((const short*)wpl + (((c*2 + half)*128) + jt*32 + lj)*8);
                #pragma unroll
                for (int c = 0; c < 4; ++c) {
                    const short8 afh = *(const short8*)hchunk(hilo, rt*32 + lj, c*2 + half);
                    acc = __builtin_amdgcn_mfma_f32_32x32x16_bf16(afh, bfh[c], acc, 0, 0, 0);
                }
                #pragma unroll
                for (int c = 0; c < 4; ++c) {
                    const short8 afh = *(const short8*)hchunk(hilo, rt*32 + lj, c*2 + half);
                    const short8 bfl = *(const short8*)((const short*)wpl + 8192 + (((c*2 + half)*128) + jt*32 + lj)*8);
                    acc = __builtin_amdgcn_mfma_f32_32x32x16_bf16(afh, bfl, acc, 0, 0, 0);
                }
                #pragma unroll
                for (int c = 0; c < 4; ++c) {
                    const short8 afl = *(const short8*)hchunk(hilo, rt*32 + lj, 8 + c*2 + half);
                    acc = __builtin_amdgcn_mfma_f32_32x32x16_bf16(afl, bfh[c], acc, 0, 0, 0);
                }
                if (wg == 0) {
                    const int col = jt*32 + lj;
                    const float bias = bcl[col];
                    #pragma unroll
                    for (int reg = 0; reg < 16; ++reg) {
                        const int row = (reg & 3) + 8*(reg >> 2) + 4*half + rt*32;
                        ag[(size_t)row*64 + col] = acc[reg] + bias;
                    }
                } else {
                    if (q2 == 0) accs0 = acc; else accs1 = acc;
                }
            }
            __syncthreads();   // all sort-r1 keys reads done -> bs may overwrite keys
            if (wg == 1) {
                #pragma unroll
                for (int q2 = 0; q2 < 2; ++q2) {
                    const floatx16 acc = q2 ? accs1 : accs0;
                    const int colb = q2*32 + lj;
                    #pragma unroll
                    for (int reg = 0; reg < 16; ++reg) {
                        const int row = (reg & 3) + 8*(reg >> 2) + 4*half + rt*32;
                        bs[row*68 + colb] = f_to_key(bf_rne(acc[reg]));
                    }
                }
            }
        }
        __syncthreads();   // bs ready; nnidx visible; hilo reads done -> may be rewritten

        // ---- aggregation: out = elu(a + max_nn b) via v_pk_max_u16 on order-keys ----
        {
            const int q = lane >> 4, fq = lane & 15;
            float4 psum = make_float4(0.f, 0.f, 0.f, 0.f);
            #pragma unroll 1
            for (int rg = 0; rg < 4; ++rg) {
                const int row = w*16 + rg*4 + q;
                unsigned mk0 = 0u, mk1 = 0u;   // key 0 is below every real key
                #pragma unroll
                for (int c = 0; c < 6; ++c) {
                    const unsigned pk = nnidx[row*6 + c];
                    #pragma unroll
                    for (int e = 0; e < 4; ++e) {
                        const int j = (pk >> (8*e)) & 127;
                        const uint2 bb = *(const uint2*)(bs + j*68 + fq*4);
                        mk0 = pk_max_u16(mk0, bb.x);
                        mk1 = pk_max_u16(mk1, bb.y);
                    }
                }
                const float4 av = *(const float4*)(ag + (size_t)row*64 + fq*4);
                float4 o;
                o.x = elu_f(av.x + key_to_f(mk0 & 0xFFFFu));
                o.y = elu_f(av.y + key_to_f(mk0 >> 16));
                o.z = elu_f(av.z + key_to_f(mk1 & 0xFFFFu));
                o.w = elu_f(av.w + key_to_f(mk1 >> 16));

                if (L < 2) {
                    unsigned short hx,lx,hy,ly,hz,lz,hw2,lw2;
                    split_bf16(o.x,hx,lx); split_bf16(o.y,hy,ly);
                    split_bf16(o.z,hz,lz); split_bf16(o.w,hw2,lw2);
                    *(uint2*)(hchunk(hilo, row, fq >> 1) + (fq & 1)*4) =
                        make_uint2((unsigned)hx | ((unsigned)hy << 16), (unsigned)hz | ((unsigned)hw2 << 16));
                    *(uint2*)(hchunk(hilo, row, 8 + (fq >> 1)) + (fq & 1)*4) =
                        make_uint2((unsigned)lx | ((unsigned)ly << 16), (unsigned)lz | ((unsigned)lw2 << 16));
                    float sp = o.x*o.x + o.y*o.y + o.z*o.z + o.w*o.w;
                    sp += __shfl_xor(sp, 1);
                    sp += __shfl_xor(sp, 2);
                    sp += __shfl_xor(sp, 4);
                    sp += __shfl_xor(sp, 8);
                    if (fq == 0) sqs[row] = sp;
                } else {
                    psum.x += o.x; psum.y += o.y; psum.z += o.z; psum.w += o.w;
                }
            }
            if (L < 2) {
                __syncthreads();   // next layer sees new hilo + sqs; bs reads done
            } else {
                __syncthreads();   // nnidx/bs reads done -> pool8 may alias
                float* pool8 = (float*)(arena + 33280);   // [8][64]
                psum.x += __shfl_xor(psum.x, 16); psum.y += __shfl_xor(psum.y, 16);
                psum.z += __shfl_xor(psum.z, 16); psum.w += __shfl_xor(psum.w, 16);
                psum.x += __shfl_xor(psum.x, 32); psum.y += __shfl_xor(psum.y, 32);
                psum.z += __shfl_xor(psum.z, 32); psum.w += __shfl_xor(psum.w, 32);
                if (q == 0) *(float4*)(pool8 + w*64 + fq*4) = psum;
                __syncthreads();
                // ---- fused head MLP (wave 0 only; same-wave LDS deps need no barrier) ----
                if (t < 64) {
                    float s = 0.0f;
                    #pragma unroll
                    for (int k = 0; k < 8; ++k) s += pool8[k*64 + t];
                    float* P  = (float*)(arena + 35328);   // 64 | O1 64 | O2 32 | O3 32 | O4 8
                    float* O1 = P + 64;
                    float* O2 = O1 + 64;
                    float* O3 = O2 + 32;
                    float* O4 = O3 + 32;
                    P[t] = s;
                    float a1 = bo1[t];
                    #pragma unroll
                    for (int k = 0; k < 64; ++k) a1 = fmaf(P[k], wo1[k*64 + t], a1);
                    O1[t] = elu_f(a1);
                    if (t < 32) {
                        float a2 = bo2[t];
                        #pragma unroll
                        for (int k = 0; k < 64; ++k) a2 = fmaf(O1[k], wo2[k*32 + t], a2);
                        O2[t] = elu_f(a2);
                        float a3 = bo3[t];
                        #pragma unroll
                        for (int k = 0; k < 32; ++k) a3 = fmaf(O2[k], wo3[k*32 + t], a3);
                        O3[t] = elu_f(a3);
                    }
                    if (t < 8) {
                        float a4 = bo4[t];
                        #pragma unroll
                        for (int k = 0; k < 32; ++k) a4 = fmaf(O3[k], wo4[k*8 + t], a4);
                        O4[t] = elu_f(a4);
                    }
                    if (t == 0) {
                        float a5 = bo5[0];
                        #pragma unroll
                        for (int k = 0; k < 8; ++k) a5 = fmaf(O4[k], wo5[k], a5);
                        outp[g] = a5;
                    }
                }
            }
        }
    }
}

extern "C" void kernel_launch(void* const* d_in, const int* in_sizes, int n_in,
                              void* d_out, int out_size, void* d_ws, size_t ws_size,
                              hipStream_t stream) {
    const float* x_pf = (const float*)d_in[0];
    const float* we1 = (const float*)d_in[2];
    const float* be1 = (const float*)d_in[3];
    const float* we2 = (const float*)d_in[4];
    const float* be2 = (const float*)d_in[5];
    const float* wc1 = (const float*)d_in[6];
    const float* bc1 = (const float*)d_in[7];
    const float* wc2 = (const float*)d_in[8];
    const float* bc2 = (const float*)d_in[9];
    const float* wc3 = (const float*)d_in[10];
    const float* bc3 = (const float*)d_in[11];
    const float* wo1 = (const float*)d_in[12];
    const float* bo1 = (const float*)d_in[13];
    const float* wo2 = (const float*)d_in[14];
    const float* bo2 = (const float*)d_in[15];
    const float* wo3 = (const float*)d_in[16];
    const float* bo3 = (const float*)d_in[17];
    const float* wo4 = (const float*)d_in[18];
    const float* bo4 = (const float*)d_in[19];
    const float* wo5 = (const float*)d_in[20];
    const float* bo5 = (const float*)d_in[21];

    float* out = (float*)d_out;           // [0:512) outputs, [512:) batch ids (as float)
    char* ws = (char*)d_ws;
    float* abuf = (float*)ws;                                              // 16 MB
    unsigned short* wpack = (unsigned short*)(ws + (size_t)16*1024*1024);  // 112 KB

    pack_w<<<112, 256, 0, stream>>>(wc1, wc2, wc3, we2, wpack);

    conv_all<<<NG, 512, 0, stream>>>(x_pf, wpack, bc1, bc2, bc3,
        we1, be1, wpack + 49152, be2,
        wo1, bo1, wo2, bo2, wo3, bo3, wo4, bo4, wo5, bo5,
        abuf, out, out + NG);
}

// Round 6
// 235.628 us; speedup vs baseline: 1.0683x; 1.0683x over previous
//
#include <hip/hip_runtime.h>
#include <math.h>

#define NG 512
#define NP 128
#define HID 64
#define KNN 24
#define NTOT (NG*NP)

typedef __attribute__((ext_vector_type(8)))  short  short8;
typedef __attribute__((ext_vector_type(16))) float  floatx16;

__device__ __forceinline__ float elu_f(float v) {
    const float e = __builtin_amdgcn_exp2f(v * 1.442695040888963f) - 1.0f;
    return v > 0.0f ? v : e;
}

__device__ __forceinline__ void split_bf16(float x, unsigned short& hb, unsigned short& lb) {
    unsigned u = __float_as_uint(x);
    unsigned h = (u + 0x7FFFu + ((u >> 16) & 1u)) >> 16;
    hb = (unsigned short)h;
    float hf = __uint_as_float(h << 16);
    float lo = x - hf;
    unsigned v = __float_as_uint(lo);
    lb = (unsigned short)((v + 0x7FFFu + ((v >> 16) & 1u)) >> 16);
}
__device__ __forceinline__ unsigned short bf_rne(float x) {
    unsigned u = __float_as_uint(x);
    return (unsigned short)((u + 0x7FFFu + ((u >> 16) & 1u)) >> 16);
}
__device__ __forceinline__ float bf_lo(unsigned u) { return __uint_as_float(u << 16); }
__device__ __forceinline__ float bf_hi(unsigned u) { return __uint_as_float(u & 0xFFFF0000u); }

// order-preserving bf16 <-> u16 key map (monotone: unsigned compare == float compare)
__device__ __forceinline__ unsigned short f_to_key(unsigned short b) {
    return (unsigned short)(b ^ ((b & 0x8000u) ? 0xFFFFu : 0x8000u));
}
__device__ __forceinline__ float key_to_f(unsigned k) {
    const unsigned bf = (k & 0x8000u) ? (k ^ 0x8000u) : (k ^ 0xFFFFu);
    return __uint_as_float(bf << 16);
}
__device__ __forceinline__ unsigned pk_max_u16(unsigned a, unsigned b) {
    unsigned d;
    asm("v_pk_max_u16 %0, %1, %2" : "=v"(d) : "v"(a), "v"(b));
    return d;
}

// XOR-swizzled hilo accessor: row = 16 chunks of 16B (hi ch 0..7, lo ch 8..15).
__device__ __forceinline__ unsigned short* hchunk(unsigned short* base, int row, int ch) {
    return base + (((row << 4) + (ch ^ (row & 15))) << 3);
}
__device__ __forceinline__ const unsigned short* hchunk(const unsigned short* base, int row, int ch) {
    return base + (((row << 4) + (ch ^ (row & 15))) << 3);
}

// bitonic sort 8 ascending
__device__ __forceinline__ void sort8_asc(unsigned* y) {
    #pragma unroll
    for (int k = 2; k <= 8; k <<= 1)
        #pragma unroll
        for (int j = k >> 1; j > 0; j >>= 1)
            #pragma unroll
            for (int i = 0; i < 8; ++i) {
                const int l = i ^ j;
                if (l > i) {
                    const bool up = ((i & k) == 0);
                    const unsigned a = y[i], b = y[l];
                    const unsigned mn = a < b ? a : b;
                    const unsigned mx = a < b ? b : a;
                    y[i] = up ? mn : mx;
                    y[l] = up ? mx : mn;
                }
            }
}

// x[0..23] asc ++ x[24..31] desc (bitonic) -> keep smallest 24 sorted
__device__ __forceinline__ void merge_top24(unsigned* x) {
    #pragma unroll
    for (int d = 16; d > 0; d >>= 1)
        #pragma unroll
        for (int i = 0; i < 32; ++i)
            if (!(i & d) && i < 24) {
                const int l = i | d;
                const unsigned a = x[i], b = x[l];
                x[i] = a < b ? a : b;
                x[l] = a < b ? b : a;
            }
}

// merge my sorted-24 list with lane (lane^mask)'s sorted-24 list, keep smallest 24.
__device__ __forceinline__ void merge2_shfl(unsigned* xk, int mask) {
    unsigned z[32];
    #pragma unroll
    for (int e = 0; e < 24; ++e) {
        const unsigned ye = (unsigned)__shfl_xor((int)xk[23 - e], mask);
        z[8 + e] = xk[e] < ye ? xk[e] : ye;
    }
    #pragma unroll
    for (int d = 16; d > 0; d >>= 1)
        #pragma unroll
        for (int i = 8; i < 32; ++i)
            if (!(i & d)) {
                const int l = i | d;
                const unsigned a = z[i], b = z[l];
                z[i] = a < b ? a : b;
                z[l] = a < b ? b : a;
            }
    #pragma unroll
    for (int e = 0; e < 24; ++e) xk[e] = z[8 + e];
}

// ---------------- pack weights into MFMA-B-fragment-ready hi/lo bf16 layout ----------------
__global__ __launch_bounds__(256) void pack_w(
    const float* __restrict__ wc1, const float* __restrict__ wc2, const float* __restrict__ wc3,
    const float* __restrict__ we2,
    unsigned short* __restrict__ wp)
{
    const int n = blockIdx.x*256 + threadIdx.x;      // 0..28671
    if (n < 24576) {
        const int layer = n >> 13;
        const int r = n & 8191;
        const int e = r & 7, j = (r >> 3) & 127, ch = r >> 10;
        const int k = (ch >> 1)*16 + (ch & 1)*8 + e;
        const float* wc = (layer == 0) ? wc1 : ((layer == 1) ? wc2 : wc3);
        float w;
        if (j < 64) w = wc[k*64 + j] - wc[(k+64)*64 + j];
        else        w = wc[(k+64)*64 + (j-64)];
        unsigned short hb, lb;
        split_bf16(w, hb, lb);
        unsigned short* base = wp + layer*16384;
        base[r] = hb;
        base[8192 + r] = lb;
    } else if (n < 24576 + 4096) {
        const int m = n - 24576;
        const int e = m & 7, col = (m >> 3) & 63, ch = m >> 9;
        const int k = (ch >> 1)*16 + (ch & 1)*8 + e;
        unsigned short hb, lb;
        split_bf16(we2[k*64 + col], hb, lb);
        unsigned short* base = wp + 49152;
        base[m] = hb;
        base[4096 + m] = lb;
    }
}

// ---------------- single fused kernel: encoder + 3 conv layers + pooling + head MLP ----------------
// 512 threads (8 waves), one graph per block. Grid=512 => 2 blocks/CU; LDS up to 80KB free.
// Arena (69632 B):
//   keys  [128][65] u32 @0      (33280; aliases prologue staging, bs key-bf16[128][68] in ab/agg)
//   nnidx [128][6]  u32 @33280  ( 3072; aliases pool8[8][64] @33280 + head scratch @35328 in epilogue)
//   hilo  swizzled bf16 @36352  (32768)
//   sqs   [128] f32 @69120      (  512)
// Pressure rule (r2/r5 lessons): NO new value may live across a __syncthreads().
__global__ __launch_bounds__(512, 4) void conv_all(
    const float* __restrict__ x,
    const unsigned short* __restrict__ wp,
    const float* __restrict__ bc1, const float* __restrict__ bc2, const float* __restrict__ bc3,
    const float* __restrict__ we1, const float* __restrict__ be1,
    const unsigned short* __restrict__ we2p, const float* __restrict__ be2,
    const float* __restrict__ wo1, const float* __restrict__ bo1,
    const float* __restrict__ wo2, const float* __restrict__ bo2,
    const float* __restrict__ wo3, const float* __restrict__ bo3,
    const float* __restrict__ wo4, const float* __restrict__ bo4,
    const float* __restrict__ wo5, const float* __restrict__ bo5,
    float* __restrict__ ag_all, float* __restrict__ outp, float* __restrict__ out_batch)
{
    __shared__ __align__(16) char arena[69632];
    unsigned*        keys  = (unsigned*)arena;
    unsigned*        nnidx = (unsigned*)(arena + 33280);
    unsigned short*  hilo  = (unsigned short*)(arena + 36352);
    float*           sqs   = (float*)(arena + 69120);

    const int g = blockIdx.x;
    const int t = threadIdx.x;
    const int w = t >> 6, lane = t & 63;
    const int lj = lane & 31, half = lane >> 5;
    const int rt = w & 3, wg = w >> 2;
    float* __restrict__ ag = ag_all + (size_t)g * (NP*HID);

    // ================= encoder prologue =================
    {
        float* w1s = (float*)arena;            // [4][64]
        float* b1v = (float*)(arena + 1024);   // [64]
        float* b2v = (float*)(arena + 1280);   // [64]
        if (t < 256) w1s[t] = we1[t];
        else if (t < 320) b1v[t-256] = be1[t-256];
        else if (t < 384) b2v[t-320] = be2[t-320];
        if (t < 128) out_batch[(size_t)g*128 + t] = (float)g;
        __syncthreads();

        // layer 1: n = node, fh = col-half (16-wide quarters)
        const int n = t & 127, fh = t >> 7, f0 = fh*16;
        const float4 xv = ((const float4*)x)[g*128 + n];
        float acc1[16];
        #pragma unroll
        for (int q = 0; q < 4; ++q) {
            const float4 b4 = *(const float4*)(b1v + f0 + q*4);
            acc1[q*4+0] = b4.x; acc1[q*4+1] = b4.y; acc1[q*4+2] = b4.z; acc1[q*4+3] = b4.w;
        }
        #pragma unroll
        for (int k = 0; k < 4; ++k) {
            const float xk_ = (k == 0) ? xv.x : (k == 1) ? xv.y : (k == 2) ? xv.z : xv.w;
            #pragma unroll
            for (int q = 0; q < 4; ++q) {
                const float4 w4 = *(const float4*)(w1s + k*64 + f0 + q*4);
                acc1[q*4+0] = fmaf(xk_, w4.x, acc1[q*4+0]);
                acc1[q*4+1] = fmaf(xk_, w4.y, acc1[q*4+1]);
                acc1[q*4+2] = fmaf(xk_, w4.z, acc1[q*4+2]);
                acc1[q*4+3] = fmaf(xk_, w4.w, acc1[q*4+3]);
            }
        }
        unsigned hu[8], lu[8];
        #pragma unroll
        for (int e = 0; e < 8; ++e) {
            const float v0 = elu_f(acc1[2*e]), v1 = elu_f(acc1[2*e+1]);
            unsigned short h0, l0, h1, l1;
            split_bf16(v0, h0, l0); split_bf16(v1, h1, l1);
            hu[e] = (unsigned)h0 | ((unsigned)h1 << 16);
            lu[e] = (unsigned)l0 | ((unsigned)l1 << 16);
        }
        *(uint4*)hchunk(hilo, n, fh*2)       = make_uint4(hu[0], hu[1], hu[2], hu[3]);
        *(uint4*)hchunk(hilo, n, fh*2 + 1)   = make_uint4(hu[4], hu[5], hu[6], hu[7]);
        *(uint4*)hchunk(hilo, n, 8 + fh*2)   = make_uint4(lu[0], lu[1], lu[2], lu[3]);
        *(uint4*)hchunk(hilo, n, 8 + fh*2+1) = make_uint4(lu[4], lu[5], lu[6], lu[7]);
        __syncthreads();

        // layer 2 via MFMA: 8 tiles = (rt, jt2=wg), loads interleaved with MFMAs
        const int jt2 = wg;
        floatx16 acc = {0.f,0.f,0.f,0.f,0.f,0.f,0.f,0.f,0.f,0.f,0.f,0.f,0.f,0.f,0.f,0.f};
        #pragma unroll
        for (int p = 0; p < 3; ++p) {
            const int aSel = (p == 2) ? 8 : 0;
            const int part = (p == 1) ? 1 : 0;
            #pragma unroll
            for (int c = 0; c < 4; ++c) {
                const short8 af  = *(const short8*)hchunk(hilo, rt*32 + lj, aSel + c*2 + half);
                const short8 bf4 = *(const short8*)((const short*)we2p + part*4096 + (((c*2 + half)*64) + jt2*32 + lj)*8);
                acc = __builtin_amdgcn_mfma_f32_32x32x16_bf16(af, bf4, acc, 0, 0, 0);
            }
        }
        const int col = jt2*32 + lj;
        const float bias = ((const float*)(arena + 1280))[col];
        __syncthreads();   // all layer-2 hilo reads done before overwrite
        #pragma unroll
        for (int reg = 0; reg < 16; ++reg) {
            const int row = (reg & 3) + 8*(reg >> 2) + 4*half + rt*32;
            const float v = elu_f(acc[reg] + bias);
            unsigned short hb, lb;
            split_bf16(v, hb, lb);
            *(hchunk(hilo, row, col >> 3) + (col & 7))       = hb;
            *(hchunk(hilo, row, 8 + (col >> 3)) + (col & 7)) = lb;
        }
        __syncthreads();

        // sq read-back: r = node, cq = col-quarter
        const int r = t >> 2, cq = t & 3, c0 = cq*2;
        const uint4 h0 = *(const uint4*)hchunk(hilo, r, c0);
        const uint4 h1 = *(const uint4*)hchunk(hilo, r, c0+1);
        const uint4 l0 = *(const uint4*)hchunk(hilo, r, 8+c0);
        const uint4 l1 = *(const uint4*)hchunk(hilo, r, 8+c0+1);
        float s = 0.0f;
        const unsigned hh[8] = {h0.x,h0.y,h0.z,h0.w,h1.x,h1.y,h1.z,h1.w};
        const unsigned ll[8] = {l0.x,l0.y,l0.z,l0.w,l1.x,l1.y,l1.z,l1.w};
        #pragma unroll
        for (int e = 0; e < 8; ++e) {
            const float va = bf_lo(hh[e]) + bf_lo(ll[e]);
            const float vb = bf_hi(hh[e]) + bf_hi(ll[e]);
            s = fmaf(va, va, s); s = fmaf(vb, vb, s);
        }
        s += __shfl_xor(s, 1);
        s += __shfl_xor(s, 2);
        if (cq == 0) sqs[r] = s;
        __syncthreads();
    }

    // ================= 3 conv layers =================
    #pragma unroll 1
    for (int L = 0; L < 3; ++L) {
        const unsigned short* wpl = wp + L*16384;
        const float* bcl = (L == 0) ? bc1 : (L == 1) ? bc2 : bc3;

        // ---- Gram rounds (2 tiles/round, all 8 waves) + batched-bitonic top-k ----
        unsigned xk[32];
        #pragma unroll
        for (int s = 0; s < 24; ++s) xk[s] = 0xFFFFFFFFu;

        #pragma unroll 1
        for (int r = 0; r < 2; ++r) {
            const int jt = r*2 + wg;
            {
                floatx16 acc = {0.f,0.f,0.f,0.f,0.f,0.f,0.f,0.f,0.f,0.f,0.f,0.f,0.f,0.f,0.f,0.f};
                #pragma unroll
                for (int p = 0; p < 3; ++p) {
                    const int aSel = (p == 2) ? 8 : 0;
                    const int bSel = (p == 1) ? 8 : 0;
                    #pragma unroll
                    for (int c = 0; c < 4; ++c) {
                        const short8 af = *(const short8*)hchunk(hilo, rt*32 + lj, aSel + c*2 + half);
                        const short8 bf = *(const short8*)hchunk(hilo, jt*32 + lj, bSel + c*2 + half);
                        acc = __builtin_amdgcn_mfma_f32_32x32x16_bf16(af, bf, acc, 0, 0, 0);
                    }
                }
                const unsigned jg = (unsigned)(jt*32 + lj);
                const float sqj = sqs[jg];
                #pragma unroll
                for (int reg = 0; reg < 16; ++reg) {
                    const int i = (reg & 3) + 8*(reg >> 2) + 4*half + rt*32;
                    float d = fmaf(-2.0f, acc[reg], sqs[i] + sqj);
                    d = fmaxf(d, 0.0f);
                    keys[i*65 + wg*32 + lj] = (__float_as_uint(d) & 0xFFFFFF80u) | jg;
                }
            }
            __syncthreads();
            {
                // sort ownership: row = t>>2, seg = t&3 -> absorb 16 new keys
                const unsigned* kr = keys + (t >> 2)*65 + (t & 3)*16;
                const uint4 k0 = *(const uint4*)kr;
                const uint4 k1 = *(const uint4*)(kr + 4);
                {
                    unsigned y[8] = {k0.x, k0.y, k0.z, k0.w, k1.x, k1.y, k1.z, k1.w};
                    sort8_asc(y);
                    #pragma unroll
                    for (int e = 0; e < 8; ++e) xk[24+e] = y[7-e];
                    merge_top24(xk);
                }
                const uint4 k2 = *(const uint4*)(kr + 8);
                const uint4 k3 = *(const uint4*)(kr + 12);
                {
                    unsigned y[8] = {k2.x, k2.y, k2.z, k2.w, k3.x, k3.y, k3.z, k3.w};
                    sort8_asc(y);
                    #pragma unroll
                    for (int e = 0; e < 8; ++e) xk[24+e] = y[7-e];
                    merge_top24(xk);
                }
            }
            __syncthreads();   // keys reads done -> next round may overwrite (or bs alias)
        }

        // ---- cross-lane tree merge (adjacent lanes hold the row's 4 segment lists) ----
        merge2_shfl(xk, 1);
        merge2_shfl(xk, 2);
        if ((t & 3) == 0) {
            #pragma unroll
            for (int c = 0; c < 6; ++c)
                nnidx[(t >> 2)*6 + c] = (xk[c*4] & 127u) | ((xk[c*4+1] & 127u) << 8)
                                      | ((xk[c*4+2] & 127u) << 16) | ((xk[c*4+3] & 127u) << 24);
        }
        // no barrier needed here: bs (aliases keys) is safe post the r=1 trailing barrier;
        // nnidx becomes visible via the ab->agg barrier below.

        // ---- ab-GEMM: waves 0-3 -> a (global, +bias), waves 4-7 -> b (LDS key-bf16) ----
        unsigned short* bs = (unsigned short*)arena;   // [128][68] order-key bf16
        {
            short8 afr[8];
            #pragma unroll
            for (int sel = 0; sel < 2; ++sel)
                #pragma unroll
                for (int c = 0; c < 4; ++c)
                    afr[sel*4+c] = *(const short8*)hchunk(hilo, rt*32 + lj, sel*8 + c*2 + half);

            #pragma unroll 1
            for (int q2 = 0; q2 < 2; ++q2) {
                const int jt = wg*2 + q2;
                short8 bfr[8];
                #pragma unroll
                for (int part = 0; part < 2; ++part)
                    #pragma unroll
                    for (int c = 0; c < 4; ++c)
                        bfr[part*4+c] = *(const short8*)((const short*)wpl + part*8192 + (((c*2 + half)*128) + jt*32 + lj)*8);
                floatx16 acc = {0.f,0.f,0.f,0.f,0.f,0.f,0.f,0.f,0.f,0.f,0.f,0.f,0.f,0.f,0.f,0.f};
                #pragma unroll
                for (int c = 0; c < 4; ++c) acc = __builtin_amdgcn_mfma_f32_32x32x16_bf16(afr[c],   bfr[c],   acc, 0, 0, 0);
                #pragma unroll
                for (int c = 0; c < 4; ++c) acc = __builtin_amdgcn_mfma_f32_32x32x16_bf16(afr[c],   bfr[4+c], acc, 0, 0, 0);
                #pragma unroll
                for (int c = 0; c < 4; ++c) acc = __builtin_amdgcn_mfma_f32_32x32x16_bf16(afr[4+c], bfr[c],   acc, 0, 0, 0);

                if (wg == 0) {
                    const int col = jt*32 + lj;
                    const float bias = bcl[col];
                    #pragma unroll
                    for (int reg = 0; reg < 16; ++reg) {
                        const int row = (reg & 3) + 8*(reg >> 2) + 4*half + rt*32;
                        ag[(size_t)row*64 + col] = acc[reg] + bias;
                    }
                } else {
                    const int colb = q2*32 + lj;
                    #pragma unroll
                    for (int reg = 0; reg < 16; ++reg) {
                        const int row = (reg & 3) + 8*(reg >> 2) + 4*half + rt*32;
                        bs[row*68 + colb] = f_to_key(bf_rne(acc[reg]));
                    }
                }
            }
        }
        __syncthreads();   // bs/ag/nnidx ready; hilo reads done -> may be rewritten

        // ---- aggregation: out = elu(a + max_nn b) via v_pk_max_u16 on order-keys ----
        {
            const int q = lane >> 4, fq = lane & 15;
            float4 psum = make_float4(0.f, 0.f, 0.f, 0.f);
            #pragma unroll 1
            for (int rg = 0; rg < 4; ++rg) {
                const int row = w*16 + rg*4 + q;
                unsigned mk0 = 0u, mk1 = 0u;   // key 0 is below every real key
                #pragma unroll
                for (int c = 0; c < 6; ++c) {
                    const unsigned pk = nnidx[row*6 + c];
                    #pragma unroll
                    for (int e = 0; e < 4; ++e) {
                        const int j = (pk >> (8*e)) & 127;
                        const uint2 bb = *(const uint2*)(bs + j*68 + fq*4);
                        mk0 = pk_max_u16(mk0, bb.x);
                        mk1 = pk_max_u16(mk1, bb.y);
                    }
                }
                const float4 av = *(const float4*)(ag + (size_t)row*64 + fq*4);
                float4 o;
                o.x = elu_f(av.x + key_to_f(mk0 & 0xFFFFu));
                o.y = elu_f(av.y + key_to_f(mk0 >> 16));
                o.z = elu_f(av.z + key_to_f(mk1 & 0xFFFFu));
                o.w = elu_f(av.w + key_to_f(mk1 >> 16));

                if (L < 2) {
                    unsigned short hx,lx,hy,ly,hz,lz,hw2,lw2;
                    split_bf16(o.x,hx,lx); split_bf16(o.y,hy,ly);
                    split_bf16(o.z,hz,lz); split_bf16(o.w,hw2,lw2);
                    *(uint2*)(hchunk(hilo, row, fq >> 1) + (fq & 1)*4) =
                        make_uint2((unsigned)hx | ((unsigned)hy << 16), (unsigned)hz | ((unsigned)hw2 << 16));
                    *(uint2*)(hchunk(hilo, row, 8 + (fq >> 1)) + (fq & 1)*4) =
                        make_uint2((unsigned)lx | ((unsigned)ly << 16), (unsigned)lz | ((unsigned)lw2 << 16));
                    float sp = o.x*o.x + o.y*o.y + o.z*o.z + o.w*o.w;
                    sp += __shfl_xor(sp, 1);
                    sp += __shfl_xor(sp, 2);
                    sp += __shfl_xor(sp, 4);
                    sp += __shfl_xor(sp, 8);
                    if (fq == 0) sqs[row] = sp;
                } else {
                    psum.x += o.x; psum.y += o.y; psum.z += o.z; psum.w += o.w;
                }
            }
            if (L < 2) {
                __syncthreads();   // next layer sees new hilo + sqs; bs reads done
            } else {
                __syncthreads();   // nnidx/bs reads done -> pool8 may alias
                float* pool8 = (float*)(arena + 33280);   // [8][64]
                psum.x += __shfl_xor(psum.x, 16); psum.y += __shfl_xor(psum.y, 16);
                psum.z += __shfl_xor(psum.z, 16); psum.w += __shfl_xor(psum.w, 16);
                psum.x += __shfl_xor(psum.x, 32); psum.y += __shfl_xor(psum.y, 32);
                psum.z += __shfl_xor(psum.z, 32); psum.w += __shfl_xor(psum.w, 32);
                if (q == 0) *(float4*)(pool8 + w*64 + fq*4) = psum;
                __syncthreads();
                // ---- fused head MLP (wave 0 only; same-wave LDS deps need no barrier) ----
                if (t < 64) {
                    float s = 0.0f;
                    #pragma unroll
                    for (int k = 0; k < 8; ++k) s += pool8[k*64 + t];
                    float* P  = (float*)(arena + 35328);   // 64 | O1 64 | O2 32 | O3 32 | O4 8
                    float* O1 = P + 64;
                    float* O2 = O1 + 64;
                    float* O3 = O2 + 32;
                    float* O4 = O3 + 32;
                    P[t] = s;
                    float a1 = bo1[t];
                    #pragma unroll
                    for (int k = 0; k < 64; ++k) a1 = fmaf(P[k], wo1[k*64 + t], a1);
                    O1[t] = elu_f(a1);
                    if (t < 32) {
                        float a2 = bo2[t];
                        #pragma unroll
                        for (int k = 0; k < 64; ++k) a2 = fmaf(O1[k], wo2[k*32 + t], a2);
                        O2[t] = elu_f(a2);
                        float a3 = bo3[t];
                        #pragma unroll
                        for (int k = 0; k < 32; ++k) a3 = fmaf(O2[k], wo3[k*32 + t], a3);
                        O3[t] = elu_f(a3);
                    }
                    if (t < 8) {
                        float a4 = bo4[t];
                        #pragma unroll
                        for (int k = 0; k < 32; ++k) a4 = fmaf(O3[k], wo4[k*8 + t], a4);
                        O4[t] = elu_f(a4);
                    }
                    if (t == 0) {
                        float a5 = bo5[0];
                        #pragma unroll
                        for (int k = 0; k < 8; ++k) a5 = fmaf(O4[k], wo5[k], a5);
                        outp[g] = a5;
                    }
                }
            }
        }
    }
}

extern "C" void kernel_launch(void* const* d_in, const int* in_sizes, int n_in,
                              void* d_out, int out_size, void* d_ws, size_t ws_size,
                              hipStream_t stream) {
    const float* x_pf = (const float*)d_in[0];
    const float* we1 = (const float*)d_in[2];
    const float* be1 = (const float*)d_in[3];
    const float* we2 = (const float*)d_in[4];
    const float* be2 = (const float*)d_in[5];
    const float* wc1 = (const float*)d_in[6];
    const float* bc1 = (const float*)d_in[7];
    const float* wc2 = (const float*)d_in[8];
    const float* bc2 = (const float*)d_in[9];
    const float* wc3 = (const float*)d_in[10];
    const float* bc3 = (const float*)d_in[11];
    const float* wo1 = (const float*)d_in[12];
    const float* bo1 = (const float*)d_in[13];
    const float* wo2 = (const float*)d_in[14];
    const float* bo2 = (const float*)d_in[15];
    const float* wo3 = (const float*)d_in[16];
    const float* bo3 = (const float*)d_in[17];
    const float* wo4 = (const float*)d_in[18];
    const float* bo4 = (const float*)d_in[19];
    const float* wo5 = (const float*)d_in[20];
    const float* bo5 = (const float*)d_in[21];

    float* out = (float*)d_out;           // [0:512) outputs, [512:) batch ids (as float)
    char* ws = (char*)d_ws;
    float* abuf = (float*)ws;                                              // 16 MB
    unsigned short* wpack = (unsigned short*)(ws + (size_t)16*1024*1024);  // 112 KB

    pack_w<<<112, 256, 0, stream>>>(wc1, wc2, wc3, we2, wpack);

    conv_all<<<NG, 512, 0, stream>>>(x_pf, wpack, bc1, bc2, bc3,
        we1, be1, wpack + 49152, be2,
        wo1, bo1, wo2, bo2, wo3, bo3, wo4, bo4, wo5, bo5,
        abuf, out, out + NG);
}

// Round 7
// 176.114 us; speedup vs baseline: 1.4293x; 1.3379x over previous
//
#include <hip/hip_runtime.h>
#include <math.h>

#define NG 512
#define NP 128
#define HID 64
#define KNN 24
#define NTOT (NG*NP)

typedef __attribute__((ext_vector_type(8)))  short  short8;
typedef __attribute__((ext_vector_type(16))) float  floatx16;

__device__ __forceinline__ float elu_f(float v) {
    const float e = __builtin_amdgcn_exp2f(v * 1.442695040888963f) - 1.0f;
    return v > 0.0f ? v : e;
}

__device__ __forceinline__ void split_bf16(float x, unsigned short& hb, unsigned short& lb) {
    unsigned u = __float_as_uint(x);
    unsigned h = (u + 0x7FFFu + ((u >> 16) & 1u)) >> 16;
    hb = (unsigned short)h;
    float hf = __uint_as_float(h << 16);
    float lo = x - hf;
    unsigned v = __float_as_uint(lo);
    lb = (unsigned short)((v + 0x7FFFu + ((v >> 16) & 1u)) >> 16);
}
__device__ __forceinline__ unsigned short bf_rne(float x) {
    unsigned u = __float_as_uint(x);
    return (unsigned short)((u + 0x7FFFu + ((u >> 16) & 1u)) >> 16);
}
__device__ __forceinline__ float bf_lo(unsigned u) { return __uint_as_float(u << 16); }
__device__ __forceinline__ float bf_hi(unsigned u) { return __uint_as_float(u & 0xFFFF0000u); }

// order-preserving bf16 <-> u16 key map (monotone: unsigned compare == float compare)
__device__ __forceinline__ unsigned short f_to_key(unsigned short b) {
    return (unsigned short)(b ^ ((b & 0x8000u) ? 0xFFFFu : 0x8000u));
}
__device__ __forceinline__ float key_to_f(unsigned k) {
    const unsigned bf = (k & 0x8000u) ? (k ^ 0x8000u) : (k ^ 0xFFFFu);
    return __uint_as_float(bf << 16);
}
__device__ __forceinline__ unsigned pk_max_u16(unsigned a, unsigned b) {
    unsigned d;
    asm("v_pk_max_u16 %0, %1, %2" : "=v"(d) : "v"(a), "v"(b));
    return d;
}

// XOR-swizzled hilo accessor: row = 16 chunks of 16B (hi ch 0..7, lo ch 8..15).
__device__ __forceinline__ unsigned short* hchunk(unsigned short* base, int row, int ch) {
    return base + (((row << 4) + (ch ^ (row & 15))) << 3);
}
__device__ __forceinline__ const unsigned short* hchunk(const unsigned short* base, int row, int ch) {
    return base + (((row << 4) + (ch ^ (row & 15))) << 3);
}

// bitonic sort 8 ascending
__device__ __forceinline__ void sort8_asc(unsigned* y) {
    #pragma unroll
    for (int k = 2; k <= 8; k <<= 1)
        #pragma unroll
        for (int j = k >> 1; j > 0; j >>= 1)
            #pragma unroll
            for (int i = 0; i < 8; ++i) {
                const int l = i ^ j;
                if (l > i) {
                    const bool up = ((i & k) == 0);
                    const unsigned a = y[i], b = y[l];
                    const unsigned mn = a < b ? a : b;
                    const unsigned mx = a < b ? b : a;
                    y[i] = up ? mn : mx;
                    y[l] = up ? mx : mn;
                }
            }
}

// x[0..23] asc ++ x[24..31] desc (bitonic) -> keep smallest 24 sorted
__device__ __forceinline__ void merge_top24(unsigned* x) {
    #pragma unroll
    for (int d = 16; d > 0; d >>= 1)
        #pragma unroll
        for (int i = 0; i < 32; ++i)
            if (!(i & d) && i < 24) {
                const int l = i | d;
                const unsigned a = x[i], b = x[l];
                x[i] = a < b ? a : b;
                x[l] = a < b ? b : a;
            }
}

// merge my sorted-24 list with lane (lane^mask)'s sorted-24 list, keep smallest 24.
__device__ __forceinline__ void merge2_shfl(unsigned* xk, int mask) {
    unsigned z[32];
    #pragma unroll
    for (int e = 0; e < 24; ++e) {
        const unsigned ye = (unsigned)__shfl_xor((int)xk[23 - e], mask);
        z[8 + e] = xk[e] < ye ? xk[e] : ye;
    }
    #pragma unroll
    for (int d = 16; d > 0; d >>= 1)
        #pragma unroll
        for (int i = 8; i < 32; ++i)
            if (!(i & d)) {
                const int l = i | d;
                const unsigned a = z[i], b = z[l];
                z[i] = a < b ? a : b;
                z[l] = a < b ? b : a;
            }
    #pragma unroll
    for (int e = 0; e < 24; ++e) xk[e] = z[8 + e];
}

// ---------------- pack weights into MFMA-B-fragment-ready hi/lo bf16 layout ----------------
__global__ __launch_bounds__(256) void pack_w(
    const float* __restrict__ wc1, const float* __restrict__ wc2, const float* __restrict__ wc3,
    const float* __restrict__ we2,
    unsigned short* __restrict__ wp)
{
    const int n = blockIdx.x*256 + threadIdx.x;      // 0..28671
    if (n < 24576) {
        const int layer = n >> 13;
        const int r = n & 8191;
        const int e = r & 7, j = (r >> 3) & 127, ch = r >> 10;
        const int k = (ch >> 1)*16 + (ch & 1)*8 + e;
        const float* wc = (layer == 0) ? wc1 : ((layer == 1) ? wc2 : wc3);
        float w;
        if (j < 64) w = wc[k*64 + j] - wc[(k+64)*64 + j];
        else        w = wc[(k+64)*64 + (j-64)];
        unsigned short hb, lb;
        split_bf16(w, hb, lb);
        unsigned short* base = wp + layer*16384;
        base[r] = hb;
        base[8192 + r] = lb;
    } else if (n < 24576 + 4096) {
        const int m = n - 24576;
        const int e = m & 7, col = (m >> 3) & 63, ch = m >> 9;
        const int k = (ch >> 1)*16 + (ch & 1)*8 + e;
        unsigned short hb, lb;
        split_bf16(we2[k*64 + col], hb, lb);
        unsigned short* base = wp + 49152;
        base[m] = hb;
        base[4096 + m] = lb;
    }
}

// ---------------- single fused kernel: encoder + 3 dynamic-edge-conv layers + pooling ----------------
// 512 threads (8 waves), one graph per block. Grid=512 => 2 blocks/CU; LDS up to 80KB free.
// Arena (69632 B):
//   keys  [128][65] u32 @0      (33280; aliases prologue staging, bs key-bf16[128][68] in ab/agg)
//   nnidx [128][6]  u32 @33280  ( 3072; aliases pool8[8][64] f32 in final epilogue)
//   hilo  swizzled bf16 @36352  (32768)
//   sqs   [128] f32 @69120      (  512)
// Pressure rule (r2/r5/r6 lessons): NO new value may live across a __syncthreads(),
// and NO extra pointer kernel-args (r6: +11 head pointers => xk spill => +156 MB scratch).
__global__ __launch_bounds__(512, 4) void conv_all(
    const float* __restrict__ x,
    const unsigned short* __restrict__ wp,
    const float* __restrict__ bc1, const float* __restrict__ bc2, const float* __restrict__ bc3,
    const float* __restrict__ we1, const float* __restrict__ be1,
    const unsigned short* __restrict__ we2p, const float* __restrict__ be2,
    float* __restrict__ ag_all, float* __restrict__ pooled_out, float* __restrict__ out_batch)
{
    __shared__ __align__(16) char arena[69632];
    unsigned*        keys  = (unsigned*)arena;
    unsigned*        nnidx = (unsigned*)(arena + 33280);
    unsigned short*  hilo  = (unsigned short*)(arena + 36352);
    float*           sqs   = (float*)(arena + 69120);

    const int g = blockIdx.x;
    const int t = threadIdx.x;
    const int w = t >> 6, lane = t & 63;
    const int lj = lane & 31, half = lane >> 5;
    const int rt = w & 3, wg = w >> 2;
    float* __restrict__ ag = ag_all + (size_t)g * (NP*HID);

    // ================= encoder prologue =================
    {
        float* w1s = (float*)arena;            // [4][64]
        float* b1v = (float*)(arena + 1024);   // [64]
        float* b2v = (float*)(arena + 1280);   // [64]
        if (t < 256) w1s[t] = we1[t];
        else if (t < 320) b1v[t-256] = be1[t-256];
        else if (t < 384) b2v[t-320] = be2[t-320];
        if (t < 128) out_batch[(size_t)g*128 + t] = (float)g;
        __syncthreads();

        // layer 1: n = node, fh = col-half (16-wide quarters)
        const int n = t & 127, fh = t >> 7, f0 = fh*16;
        const float4 xv = ((const float4*)x)[g*128 + n];
        float acc1[16];
        #pragma unroll
        for (int q = 0; q < 4; ++q) {
            const float4 b4 = *(const float4*)(b1v + f0 + q*4);
            acc1[q*4+0] = b4.x; acc1[q*4+1] = b4.y; acc1[q*4+2] = b4.z; acc1[q*4+3] = b4.w;
        }
        #pragma unroll
        for (int k = 0; k < 4; ++k) {
            const float xk_ = (k == 0) ? xv.x : (k == 1) ? xv.y : (k == 2) ? xv.z : xv.w;
            #pragma unroll
            for (int q = 0; q < 4; ++q) {
                const float4 w4 = *(const float4*)(w1s + k*64 + f0 + q*4);
                acc1[q*4+0] = fmaf(xk_, w4.x, acc1[q*4+0]);
                acc1[q*4+1] = fmaf(xk_, w4.y, acc1[q*4+1]);
                acc1[q*4+2] = fmaf(xk_, w4.z, acc1[q*4+2]);
                acc1[q*4+3] = fmaf(xk_, w4.w, acc1[q*4+3]);
            }
        }
        unsigned hu[8], lu[8];
        #pragma unroll
        for (int e = 0; e < 8; ++e) {
            const float v0 = elu_f(acc1[2*e]), v1 = elu_f(acc1[2*e+1]);
            unsigned short h0, l0, h1, l1;
            split_bf16(v0, h0, l0); split_bf16(v1, h1, l1);
            hu[e] = (unsigned)h0 | ((unsigned)h1 << 16);
            lu[e] = (unsigned)l0 | ((unsigned)l1 << 16);
        }
        *(uint4*)hchunk(hilo, n, fh*2)       = make_uint4(hu[0], hu[1], hu[2], hu[3]);
        *(uint4*)hchunk(hilo, n, fh*2 + 1)   = make_uint4(hu[4], hu[5], hu[6], hu[7]);
        *(uint4*)hchunk(hilo, n, 8 + fh*2)   = make_uint4(lu[0], lu[1], lu[2], lu[3]);
        *(uint4*)hchunk(hilo, n, 8 + fh*2+1) = make_uint4(lu[4], lu[5], lu[6], lu[7]);
        __syncthreads();

        // layer 2 via MFMA: 8 tiles = (rt, jt2=wg), loads interleaved with MFMAs
        const int jt2 = wg;
        floatx16 acc = {0.f,0.f,0.f,0.f,0.f,0.f,0.f,0.f,0.f,0.f,0.f,0.f,0.f,0.f,0.f,0.f};
        #pragma unroll
        for (int p = 0; p < 3; ++p) {
            const int aSel = (p == 2) ? 8 : 0;
            const int part = (p == 1) ? 1 : 0;
            #pragma unroll
            for (int c = 0; c < 4; ++c) {
                const short8 af  = *(const short8*)hchunk(hilo, rt*32 + lj, aSel + c*2 + half);
                const short8 bf4 = *(const short8*)((const short*)we2p + part*4096 + (((c*2 + half)*64) + jt2*32 + lj)*8);
                acc = __builtin_amdgcn_mfma_f32_32x32x16_bf16(af, bf4, acc, 0, 0, 0);
            }
        }
        const int col = jt2*32 + lj;
        const float bias = ((const float*)(arena + 1280))[col];
        __syncthreads();   // all layer-2 hilo reads done before overwrite
        #pragma unroll
        for (int reg = 0; reg < 16; ++reg) {
            const int row = (reg & 3) + 8*(reg >> 2) + 4*half + rt*32;
            const float v = elu_f(acc[reg] + bias);
            unsigned short hb, lb;
            split_bf16(v, hb, lb);
            *(hchunk(hilo, row, col >> 3) + (col & 7))       = hb;
            *(hchunk(hilo, row, 8 + (col >> 3)) + (col & 7)) = lb;
        }
        __syncthreads();

        // sq read-back: r = node, cq = col-quarter
        const int r = t >> 2, cq = t & 3, c0 = cq*2;
        const uint4 h0 = *(const uint4*)hchunk(hilo, r, c0);
        const uint4 h1 = *(const uint4*)hchunk(hilo, r, c0+1);
        const uint4 l0 = *(const uint4*)hchunk(hilo, r, 8+c0);
        const uint4 l1 = *(const uint4*)hchunk(hilo, r, 8+c0+1);
        float s = 0.0f;
        const unsigned hh[8] = {h0.x,h0.y,h0.z,h0.w,h1.x,h1.y,h1.z,h1.w};
        const unsigned ll[8] = {l0.x,l0.y,l0.z,l0.w,l1.x,l1.y,l1.z,l1.w};
        #pragma unroll
        for (int e = 0; e < 8; ++e) {
            const float va = bf_lo(hh[e]) + bf_lo(ll[e]);
            const float vb = bf_hi(hh[e]) + bf_hi(ll[e]);
            s = fmaf(va, va, s); s = fmaf(vb, vb, s);
        }
        s += __shfl_xor(s, 1);
        s += __shfl_xor(s, 2);
        if (cq == 0) sqs[r] = s;
        __syncthreads();
    }

    // ================= 3 conv layers =================
    #pragma unroll 1
    for (int L = 0; L < 3; ++L) {
        const unsigned short* wpl = wp + L*16384;
        const float* bcl = (L == 0) ? bc1 : (L == 1) ? bc2 : bc3;

        // ---- Gram rounds (2 tiles/round, all 8 waves) + batched-bitonic top-k ----
        unsigned xk[32];
        #pragma unroll
        for (int s = 0; s < 24; ++s) xk[s] = 0xFFFFFFFFu;

        #pragma unroll 1
        for (int r = 0; r < 2; ++r) {
            const int jt = r*2 + wg;
            {
                floatx16 acc = {0.f,0.f,0.f,0.f,0.f,0.f,0.f,0.f,0.f,0.f,0.f,0.f,0.f,0.f,0.f,0.f};
                #pragma unroll
                for (int p = 0; p < 3; ++p) {
                    const int aSel = (p == 2) ? 8 : 0;
                    const int bSel = (p == 1) ? 8 : 0;
                    #pragma unroll
                    for (int c = 0; c < 4; ++c) {
                        const short8 af = *(const short8*)hchunk(hilo, rt*32 + lj, aSel + c*2 + half);
                        const short8 bf = *(const short8*)hchunk(hilo, jt*32 + lj, bSel + c*2 + half);
                        acc = __builtin_amdgcn_mfma_f32_32x32x16_bf16(af, bf, acc, 0, 0, 0);
                    }
                }
                const unsigned jg = (unsigned)(jt*32 + lj);
                const float sqj = sqs[jg];
                #pragma unroll
                for (int reg = 0; reg < 16; ++reg) {
                    const int i = (reg & 3) + 8*(reg >> 2) + 4*half + rt*32;
                    float d = fmaf(-2.0f, acc[reg], sqs[i] + sqj);
                    d = fmaxf(d, 0.0f);
                    keys[i*65 + wg*32 + lj] = (__float_as_uint(d) & 0xFFFFFF80u) | jg;
                }
            }
            __syncthreads();
            {
                // sort ownership: row = t>>2, seg = t&3 -> absorb 16 new keys
                const unsigned* kr = keys + (t >> 2)*65 + (t & 3)*16;
                const uint4 k0 = *(const uint4*)kr;
                const uint4 k1 = *(const uint4*)(kr + 4);
                {
                    unsigned y[8] = {k0.x, k0.y, k0.z, k0.w, k1.x, k1.y, k1.z, k1.w};
                    sort8_asc(y);
                    #pragma unroll
                    for (int e = 0; e < 8; ++e) xk[24+e] = y[7-e];
                    merge_top24(xk);
                }
                const uint4 k2 = *(const uint4*)(kr + 8);
                const uint4 k3 = *(const uint4*)(kr + 12);
                {
                    unsigned y[8] = {k2.x, k2.y, k2.z, k2.w, k3.x, k3.y, k3.z, k3.w};
                    sort8_asc(y);
                    #pragma unroll
                    for (int e = 0; e < 8; ++e) xk[24+e] = y[7-e];
                    merge_top24(xk);
                }
            }
            __syncthreads();   // keys reads done -> next round may overwrite (or bs alias)
        }

        // ---- cross-lane tree merge (adjacent lanes hold the row's 4 segment lists) ----
        merge2_shfl(xk, 1);
        merge2_shfl(xk, 2);
        if ((t & 3) == 0) {
            #pragma unroll
            for (int c = 0; c < 6; ++c)
                nnidx[(t >> 2)*6 + c] = (xk[c*4] & 127u) | ((xk[c*4+1] & 127u) << 8)
                                      | ((xk[c*4+2] & 127u) << 16) | ((xk[c*4+3] & 127u) << 24);
        }
        // no barrier needed here: bs (aliases keys) is safe post the r=1 trailing barrier;
        // nnidx becomes visible via the ab->agg barrier below.

        // ---- ab-GEMM: waves 0-3 -> a (global, +bias), waves 4-7 -> b (LDS key-bf16) ----
        unsigned short* bs = (unsigned short*)arena;   // [128][68] order-key bf16
        {
            short8 afr[8];
            #pragma unroll
            for (int sel = 0; sel < 2; ++sel)
                #pragma unroll
                for (int c = 0; c < 4; ++c)
                    afr[sel*4+c] = *(const short8*)hchunk(hilo, rt*32 + lj, sel*8 + c*2 + half);

            #pragma unroll 1
            for (int q2 = 0; q2 < 2; ++q2) {
                const int jt = wg*2 + q2;
                short8 bfr[8];
                #pragma unroll
                for (int part = 0; part < 2; ++part)
                    #pragma unroll
                    for (int c = 0; c < 4; ++c)
                        bfr[part*4+c] = *(const short8*)((const short*)wpl + part*8192 + (((c*2 + half)*128) + jt*32 + lj)*8);
                floatx16 acc = {0.f,0.f,0.f,0.f,0.f,0.f,0.f,0.f,0.f,0.f,0.f,0.f,0.f,0.f,0.f,0.f};
                #pragma unroll
                for (int c = 0; c < 4; ++c) acc = __builtin_amdgcn_mfma_f32_32x32x16_bf16(afr[c],   bfr[c],   acc, 0, 0, 0);
                #pragma unroll
                for (int c = 0; c < 4; ++c) acc = __builtin_amdgcn_mfma_f32_32x32x16_bf16(afr[c],   bfr[4+c], acc, 0, 0, 0);
                #pragma unroll
                for (int c = 0; c < 4; ++c) acc = __builtin_amdgcn_mfma_f32_32x32x16_bf16(afr[4+c], bfr[c],   acc, 0, 0, 0);

                if (wg == 0) {
                    const int col = jt*32 + lj;
                    const float bias = bcl[col];
                    #pragma unroll
                    for (int reg = 0; reg < 16; ++reg) {
                        const int row = (reg & 3) + 8*(reg >> 2) + 4*half + rt*32;
                        ag[(size_t)row*64 + col] = acc[reg] + bias;
                    }
                } else {
                    const int colb = q2*32 + lj;
                    #pragma unroll
                    for (int reg = 0; reg < 16; ++reg) {
                        const int row = (reg & 3) + 8*(reg >> 2) + 4*half + rt*32;
                        bs[row*68 + colb] = f_to_key(bf_rne(acc[reg]));
                    }
                }
            }
        }
        __syncthreads();   // bs/ag/nnidx ready; hilo reads done -> may be rewritten

        // ---- aggregation: out = elu(a + max_nn b) via v_pk_max_u16 on order-keys ----
        {
            const int q = lane >> 4, fq = lane & 15;
            float4 psum = make_float4(0.f, 0.f, 0.f, 0.f);
            #pragma unroll 1
            for (int rg = 0; rg < 4; ++rg) {
                const int row = w*16 + rg*4 + q;
                unsigned mk0 = 0u, mk1 = 0u;   // key 0 is below every real key
                #pragma unroll
                for (int c = 0; c < 6; ++c) {
                    const unsigned pk = nnidx[row*6 + c];
                    #pragma unroll
                    for (int e = 0; e < 4; ++e) {
                        const int j = (pk >> (8*e)) & 127;
                        const uint2 bb = *(const uint2*)(bs + j*68 + fq*4);
                        mk0 = pk_max_u16(mk0, bb.x);
                        mk1 = pk_max_u16(mk1, bb.y);
                    }
                }
                const float4 av = *(const float4*)(ag + (size_t)row*64 + fq*4);
                float4 o;
                o.x = elu_f(av.x + key_to_f(mk0 & 0xFFFFu));
                o.y = elu_f(av.y + key_to_f(mk0 >> 16));
                o.z = elu_f(av.z + key_to_f(mk1 & 0xFFFFu));
                o.w = elu_f(av.w + key_to_f(mk1 >> 16));

                if (L < 2) {
                    unsigned short hx,lx,hy,ly,hz,lz,hw2,lw2;
                    split_bf16(o.x,hx,lx); split_bf16(o.y,hy,ly);
                    split_bf16(o.z,hz,lz); split_bf16(o.w,hw2,lw2);
                    *(uint2*)(hchunk(hilo, row, fq >> 1) + (fq & 1)*4) =
                        make_uint2((unsigned)hx | ((unsigned)hy << 16), (unsigned)hz | ((unsigned)hw2 << 16));
                    *(uint2*)(hchunk(hilo, row, 8 + (fq >> 1)) + (fq & 1)*4) =
                        make_uint2((unsigned)lx | ((unsigned)ly << 16), (unsigned)lz | ((unsigned)lw2 << 16));
                    float sp = o.x*o.x + o.y*o.y + o.z*o.z + o.w*o.w;
                    sp += __shfl_xor(sp, 1);
                    sp += __shfl_xor(sp, 2);
                    sp += __shfl_xor(sp, 4);
                    sp += __shfl_xor(sp, 8);
                    if (fq == 0) sqs[row] = sp;
                } else {
                    psum.x += o.x; psum.y += o.y; psum.z += o.z; psum.w += o.w;
                }
            }
            if (L < 2) {
                __syncthreads();   // next layer sees new hilo + sqs; bs reads done
            } else {
                __syncthreads();   // nnidx reads done -> pool8 may alias
                float* pool8 = (float*)(arena + 33280);   // [8][64]
                psum.x += __shfl_xor(psum.x, 16); psum.y += __shfl_xor(psum.y, 16);
                psum.z += __shfl_xor(psum.z, 16); psum.w += __shfl_xor(psum.w, 16);
                psum.x += __shfl_xor(psum.x, 32); psum.y += __shfl_xor(psum.y, 32);
                psum.z += __shfl_xor(psum.z, 32); psum.w += __shfl_xor(psum.w, 32);
                if (q == 0) *(float4*)(pool8 + w*64 + fq*4) = psum;
                __syncthreads();
                if (t < 64) {
                    float s = 0.0f;
                    #pragma unroll
                    for (int k = 0; k < 8; ++k) s += pool8[k*64 + t];
                    pooled_out[(size_t)g*64 + t] = s;
                }
            }
        }
    }
}

// ---------------- head: 5-layer MLP on pooled[512][64] ----------------
__global__ __launch_bounds__(64) void head_kernel(
    const float* __restrict__ pooled_in,
    const float* __restrict__ wo1, const float* __restrict__ bo1,
    const float* __restrict__ wo2, const float* __restrict__ bo2,
    const float* __restrict__ wo3, const float* __restrict__ bo3,
    const float* __restrict__ wo4, const float* __restrict__ bo4,
    const float* __restrict__ wo5, const float* __restrict__ bo5,
    float* __restrict__ outp)
{
    __shared__ float pooled[64];
    __shared__ float o1[64];
    __shared__ float o2[32];
    __shared__ float o3[32];
    __shared__ float o4[8];
    const int g = blockIdx.x, t = threadIdx.x;

    pooled[t] = pooled_in[(size_t)g*64 + t];
    {
        float acc = bo1[t];
        #pragma unroll
        for (int k = 0; k < 64; ++k) acc = fmaf(pooled[k], wo1[k*64 + t], acc);
        o1[t] = elu_f(acc);
    }
    if (t < 32) {
        float acc = bo2[t];
        #pragma unroll
        for (int k = 0; k < 64; ++k) acc = fmaf(o1[k], wo2[k*32 + t], acc);
        o2[t] = elu_f(acc);
    }
    if (t < 32) {
        float acc = bo3[t];
        #pragma unroll
        for (int k = 0; k < 32; ++k) acc = fmaf(o2[k], wo3[k*32 + t], acc);
        o3[t] = elu_f(acc);
    }
    if (t < 8) {
        float acc = bo4[t];
        #pragma unroll
        for (int k = 0; k < 32; ++k) acc = fmaf(o3[k], wo4[k*8 + t], acc);
        o4[t] = elu_f(acc);
    }
    if (t == 0) {
        float acc = bo5[0];
        #pragma unroll
        for (int k = 0; k < 8; ++k) acc = fmaf(o4[k], wo5[k], acc);
        outp[g] = acc;
    }
}

extern "C" void kernel_launch(void* const* d_in, const int* in_sizes, int n_in,
                              void* d_out, int out_size, void* d_ws, size_t ws_size,
                              hipStream_t stream) {
    const float* x_pf = (const float*)d_in[0];
    const float* we1 = (const float*)d_in[2];
    const float* be1 = (const float*)d_in[3];
    const float* we2 = (const float*)d_in[4];
    const float* be2 = (const float*)d_in[5];
    const float* wc1 = (const float*)d_in[6];
    const float* bc1 = (const float*)d_in[7];
    const float* wc2 = (const float*)d_in[8];
    const float* bc2 = (const float*)d_in[9];
    const float* wc3 = (const float*)d_in[10];
    const float* bc3 = (const float*)d_in[11];
    const float* wo1 = (const float*)d_in[12];
    const float* bo1 = (const float*)d_in[13];
    const float* wo2 = (const float*)d_in[14];
    const float* bo2 = (const float*)d_in[15];
    const float* wo3 = (const float*)d_in[16];
    const float* bo3 = (const float*)d_in[17];
    const float* wo4 = (const float*)d_in[18];
    const float* bo4 = (const float*)d_in[19];
    const float* wo5 = (const float*)d_in[20];
    const float* bo5 = (const float*)d_in[21];

    float* out = (float*)d_out;           // [0:512) outputs, [512:) batch ids (as float)
    char* ws = (char*)d_ws;
    float* abuf   = (float*)(ws);                                  // 16 MB
    float* pooled = (float*)(ws + (size_t)16*1024*1024);           // 128 KB
    unsigned short* wpack = (unsigned short*)(ws + (size_t)17*1024*1024);  // 112 KB

    pack_w<<<112, 256, 0, stream>>>(wc1, wc2, wc3, we2, wpack);

    conv_all<<<NG, 512, 0, stream>>>(x_pf, wpack, bc1, bc2, bc3,
        we1, be1, wpack + 49152, be2, abuf, pooled, out + NG);

    head_kernel<<<NG, 64, 0, stream>>>(pooled, wo1, bo1, wo2, bo2, wo3, bo3, wo4, bo4, wo5, bo5, out);
}